// Round 4
// baseline (2711.608 us; speedup 1.0000x reference)
//
#include <hip/hip_runtime.h>

#define STR 260          // padded row stride (floats); 260%32=4 -> 2-way on column reads
#define NGRAPH 512

typedef float float4v __attribute__((ext_vector_type(4)));

static __device__ __forceinline__ float4v ld4(const float* p){ return *(const float4v*)p; }
static __device__ __forceinline__ void st4(float* p, float4v v){ *(float4v*)p = v; }

// ---------------- single 16x256x256 GEMM: C = act(A @ Bg + bias) ----------------
// split-K-4 over lane quads, 8x8 tiles, k-step 8 (8 barriers), B from global with
// register rotation (next-kt loads issued before current FMAs), A^T double-buffered.
template<bool RELU, bool HASBIAS>
__device__ __forceinline__ void sgemm16(const float* __restrict__ A,
                                        const float* __restrict__ Bg,
                                        const float* __restrict__ bias,
                                        float* __restrict__ C,
                                        float* __restrict__ AtSd,
                                        int tid)
{
    const int s  = tid & 3;            // K-slice (64 k each)
    const int cg = (tid >> 2) & 31;    // 8 cols
    const int rg = tid >> 7;           // 8 rows
    const int w_kt = tid & 7, w_ss = (tid >> 3) & 3, w_r = tid >> 5;   // stage map
    const int idxw = w_kt*84 + w_ss*21 + w_r;
    const int rB0  = w_r*STR + w_ss*64 + w_kt;
    const int rB1  = rB0 + 8*STR;

    __syncthreads();                   // A (LDS) written by previous phase
    AtSd[idxw]     = A[rB0];
    AtSd[idxw + 8] = A[rB1];
    __syncthreads();

    float acc[8][8];
#pragma unroll
    for (int m=0;m<8;++m)
#pragma unroll
        for (int c=0;c<8;++c) acc[m][c]=0.f;

    const float* bcol = Bg + s*64*256 + cg*8;
    for (int step = 0; step < 8; ++step) {
        const float* cur = AtSd + (step&1)*672;
        float nxt0 = 0.f, nxt1 = 0.f;
        if (step < 7) { nxt0 = A[rB0 + (step+1)*8]; nxt1 = A[rB1 + (step+1)*8]; }
        const float* bbase = bcol + step*8*256;
        float4v b0 = ld4(bbase), b1 = ld4(bbase + 4);
#pragma unroll
        for (int kt = 0; kt < 8; ++kt) {
            float4v cb0 = b0, cb1 = b1;
            if (kt < 7) { b0 = ld4(bbase + (kt+1)*256); b1 = ld4(bbase + (kt+1)*256 + 4); }
            const float* ap = cur + kt*84 + s*21 + rg*8;
            float4v a0 = ld4(ap), a1 = ld4(ap+4);
            float a[8] = {a0[0],a0[1],a0[2],a0[3],a1[0],a1[1],a1[2],a1[3]};
            float b[8] = {cb0[0],cb0[1],cb0[2],cb0[3],cb1[0],cb1[1],cb1[2],cb1[3]};
#pragma unroll
            for (int m=0;m<8;++m)
#pragma unroll
                for (int c=0;c<8;++c) acc[m][c] = fmaf(a[m], b[c], acc[m][c]);
        }
        if (step < 7) {
            float* nx = AtSd + ((step+1)&1)*672;
            nx[idxw] = nxt0; nx[idxw + 8] = nxt1;
        }
        __syncthreads();
    }
#pragma unroll
    for (int m=0;m<8;++m)
#pragma unroll
        for (int c=0;c<8;++c) {
            float v = acc[m][c];
            v += __shfl_xor(v,1);
            v += __shfl_xor(v,2);
            acc[m][c] = v;
        }
    if (s == 0) {
        const int c0 = cg*8;
#pragma unroll
        for (int m=0;m<8;++m) {
            float o[8];
#pragma unroll
            for (int c=0;c<8;++c) {
                float v = acc[m][c];
                if (HASBIAS) v += bias[c0+c];
                if (RELU)    v = fmaxf(v,0.f);
                o[c] = v;
            }
            st4(C + (rg*8+m)*STR + c0,     (float4v){o[0],o[1],o[2],o[3]});
            st4(C + (rg*8+m)*STR + c0 + 4, (float4v){o[4],o[5],o[6],o[7]});
        }
    }
}

// ------------- fused p/q GEMM: C1 = A@B1, C2 = A@B2 + bias2 (shared A^T) -------------
__device__ __forceinline__ void sgemm16_pq(const float* __restrict__ A,
                                           const float* __restrict__ B1,
                                           const float* __restrict__ B2,
                                           const float* __restrict__ bias2,
                                           float* __restrict__ C1,
                                           float* __restrict__ C2,
                                           float* __restrict__ AtSd,
                                           int tid)
{
    const int s  = tid & 3;
    const int cg = (tid >> 2) & 31;
    const int rg = tid >> 7;
    const int w_kt = tid & 7, w_ss = (tid >> 3) & 3, w_r = tid >> 5;
    const int idxw = w_kt*84 + w_ss*21 + w_r;
    const int rB0  = w_r*STR + w_ss*64 + w_kt;
    const int rB1  = rB0 + 8*STR;

    __syncthreads();
    AtSd[idxw]     = A[rB0];
    AtSd[idxw + 8] = A[rB1];
    __syncthreads();

    float accp[8][8], accq[8][8];
#pragma unroll
    for (int m=0;m<8;++m)
#pragma unroll
        for (int c=0;c<8;++c) { accp[m][c]=0.f; accq[m][c]=0.f; }

    const float* pcol = B1 + s*64*256 + cg*8;
    const float* qcol = B2 + s*64*256 + cg*8;
    for (int step = 0; step < 8; ++step) {
        const float* cur = AtSd + (step&1)*672;
        float nxt0 = 0.f, nxt1 = 0.f;
        if (step < 7) { nxt0 = A[rB0 + (step+1)*8]; nxt1 = A[rB1 + (step+1)*8]; }
        const float* pb = pcol + step*8*256;
        const float* qb = qcol + step*8*256;
        float4v p0 = ld4(pb), p1 = ld4(pb+4), q0 = ld4(qb), q1 = ld4(qb+4);
#pragma unroll
        for (int kt = 0; kt < 8; ++kt) {
            float4v cp0=p0, cp1=p1, cq0=q0, cq1=q1;
            if (kt < 7) {
                p0 = ld4(pb + (kt+1)*256); p1 = ld4(pb + (kt+1)*256 + 4);
                q0 = ld4(qb + (kt+1)*256); q1 = ld4(qb + (kt+1)*256 + 4);
            }
            const float* ap = cur + kt*84 + s*21 + rg*8;
            float4v a0 = ld4(ap), a1 = ld4(ap+4);
            float a[8]  = {a0[0],a0[1],a0[2],a0[3],a1[0],a1[1],a1[2],a1[3]};
            float bp[8] = {cp0[0],cp0[1],cp0[2],cp0[3],cp1[0],cp1[1],cp1[2],cp1[3]};
            float bq[8] = {cq0[0],cq0[1],cq0[2],cq0[3],cq1[0],cq1[1],cq1[2],cq1[3]};
#pragma unroll
            for (int m=0;m<8;++m)
#pragma unroll
                for (int c=0;c<8;++c) {
                    accp[m][c] = fmaf(a[m], bp[c], accp[m][c]);
                    accq[m][c] = fmaf(a[m], bq[c], accq[m][c]);
                }
        }
        if (step < 7) {
            float* nx = AtSd + ((step+1)&1)*672;
            nx[idxw] = nxt0; nx[idxw + 8] = nxt1;
        }
        __syncthreads();
    }
#pragma unroll
    for (int m=0;m<8;++m)
#pragma unroll
        for (int c=0;c<8;++c) {
            float v = accp[m][c];
            v += __shfl_xor(v,1); v += __shfl_xor(v,2); accp[m][c]=v;
            float w = accq[m][c];
            w += __shfl_xor(w,1); w += __shfl_xor(w,2); accq[m][c]=w;
        }
    if (s == 0) {
        const int c0 = cg*8;
#pragma unroll
        for (int m=0;m<8;++m) {
            const int r = rg*8+m;
            float op[8], oq[8];
#pragma unroll
            for (int c=0;c<8;++c) { op[c]=accp[m][c]; oq[c]=accq[m][c]+bias2[c0+c]; }
            st4(C1 + r*STR + c0,     (float4v){op[0],op[1],op[2],op[3]});
            st4(C1 + r*STR + c0 + 4, (float4v){op[4],op[5],op[6],op[7]});
            st4(C2 + r*STR + c0,     (float4v){oq[0],oq[1],oq[2],oq[3]});
            st4(C2 + r*STR + c0 + 4, (float4v){oq[4],oq[5],oq[6],oq[7]});
        }
    }
}

__global__ __launch_bounds__(256, 2)
void fcgn_kernel(const float* __restrict__ towers, const float* __restrict__ We,
                 const float* __restrict__ be,  const float* __restrict__ Wm1,
                 const float* __restrict__ bm1, const float* __restrict__ Wm2,
                 const float* __restrict__ bm2, const float* __restrict__ Wu1,
                 const float* __restrict__ bu1, const float* __restrict__ Wu2,
                 const float* __restrict__ bu2, const float* __restrict__ Wo1,
                 const float* __restrict__ bo1, const float* __restrict__ Wo2,
                 const float* __restrict__ bo2, const int* __restrict__ kPtr,
                 float* __restrict__ out)
{
    __shared__ alignas(16) float bH[16*STR];      // h -> x -> h'
    __shared__ alignas(16) float bP[16*STR];      // p / y
    __shared__ alignas(16) float bQ[16*STR];      // q
    __shared__ alignas(16) float BTB[2][8*256];   // edge Wm2 tile, 16B-slot XOR swizzle
    __shared__ alignas(16) float ATB[2][8*128];   // edge relu(p_i+q_j)^T tile (128 rows)
    __shared__ alignas(16) float AtSd[2*672];     // sgemm A^T tiles
    __shared__ float TW[224];
    __shared__ float LG[16];

    const int gid = blockIdx.x;
    const int tid = threadIdx.x;

    if (tid < 224) TW[tid] = towers[gid*224 + tid];
    __syncthreads();

    // ---- encoder: h = towers @ We + be ----
    {
        const int r = tid >> 4, u = tid & 15;
        for (int cc = 0; cc < 16; ++cc) {
            const int c = cc*16 + u;
            float sum = be[c];
#pragma unroll
            for (int f = 0; f < 14; ++f)
                sum = fmaf(TW[r*14 + f], We[f*256 + c], sum);
            bH[r*STR + c] = sum;
        }
    }

    int kk = kPtr[0];
    if (kk < 0) kk = 0;
    if (kk > 8) kk = 8;   // defensive: garbage k must not hang the GPU

    // ---- edge-phase thread mappings ----
    const int e_rg = tid >> 4;          // 16 rowgroups x 8 pair-rows (128-row chunks)
    const int e_cg = tid & 15;          // 16 colgroups x 16 cols
    int off0, off1, off2, off3;
    {
        const int s0 = 4*e_cg,  s1 = s0+1, s2 = s0+2, s3 = s0+3;
        off0 = (s0 ^ ((s0>>3)&7))*4;  off1 = (s1 ^ ((s1>>3)&7))*4;
        off2 = (s2 ^ ((s2>>3)&7))*4;  off3 = (s3 ^ ((s3>>3)&7))*4;
    }
    const int sb_kt   = tid >> 6;                       // B stage: rows kt, kt+4
    const int sb_sl   = tid & 63;
    const int sb_phys = (sb_sl ^ ((sb_sl>>3)&7))*4;
    const int sa_kt   = tid >> 5;                       // A^T stage: kt, rows r0..r0+3
    const int sa_r0   = (tid & 31)*4;
    const int sa_j0   = sa_r0 & 15;
    const int sa_il   = sa_r0 >> 4;
    const int ep_iL   = e_rg >> 1;                      // epilogue mapping
    const int ep_jB   = (e_rg & 1)*8;

    for (int rnd = 0; rnd < kk; ++rnd) {
        // p = h @ Wm1[:256] ; q = h @ Wm1[256:] + bm1 (fused)
        sgemm16_pq(bH, Wm1, Wm1 + 256*256, bm1, bP, bQ, AtSd, tid);

        // ---- edge GEMM: 256 pair-rows x 256 cols; 2 chunks x 32 k-steps of 8 ----
        __syncthreads();               // p,q visible
        {   // prologue: stage g=0 (ch=0, ks=0)
            st4(&BTB[0][ sb_kt   *256 + sb_phys], ld4(Wm2 +  sb_kt   *256 + sb_sl*4));
            st4(&BTB[0][(sb_kt+4)*256 + sb_phys], ld4(Wm2 + (sb_kt+4)*256 + sb_sl*4));
            const float pv = bP[sa_il*STR + sa_kt];
            float4v av;
#pragma unroll
            for (int c=0;c<4;++c) av[c] = fmaxf(pv + bQ[(sa_j0+c)*STR + sa_kt], 0.f);
            st4(&ATB[0][sa_kt*128 + sa_r0], av);
        }
        __syncthreads();

        float eacc[8][16];
#pragma unroll
        for (int m=0;m<8;++m)
#pragma unroll
            for (int c=0;c<16;++c) eacc[m][c]=0.f;

        for (int g = 0; g < 64; ++g) {
            const int buf = g & 1;
            const int ch = g >> 5, step = g & 31;
            // T14: prefetch g+1 into registers (global B + LDS-built A^T values)
            float4v pb0, pb1, pav;
            const int gn = g + 1, chn = gn >> 5, ksn = (gn & 31)*8, bufn = gn & 1;
            if (g < 63) {
                pb0 = ld4(Wm2 + (ksn + sb_kt  )*256 + sb_sl*4);
                pb1 = ld4(Wm2 + (ksn + sb_kt+4)*256 + sb_sl*4);
                const int k0 = ksn + sa_kt;
                const float pv = bP[(chn*8 + sa_il)*STR + k0];
#pragma unroll
                for (int c=0;c<4;++c) pav[c] = fmaxf(pv + bQ[(sa_j0+c)*STR + k0], 0.f);
            }
            // compute 8 kt x (8x16) FMA
#pragma unroll
            for (int kt = 0; kt < 8; ++kt) {
                const float* ap = &ATB[buf][kt*128 + e_rg*8];
                const float* bb = &BTB[buf][kt*256];
                float4v a0 = ld4(ap), a1 = ld4(ap+4);
                float4v b0 = ld4(bb+off0), b1 = ld4(bb+off1), b2 = ld4(bb+off2), b3 = ld4(bb+off3);
                float a[8]  = {a0[0],a0[1],a0[2],a0[3],a1[0],a1[1],a1[2],a1[3]};
                float b[16] = {b0[0],b0[1],b0[2],b0[3], b1[0],b1[1],b1[2],b1[3],
                               b2[0],b2[1],b2[2],b2[3], b3[0],b3[1],b3[2],b3[3]};
#pragma unroll
                for (int m=0;m<8;++m)
#pragma unroll
                    for (int c=0;c<16;++c) eacc[m][c] = fmaf(a[m], b[c], eacc[m][c]);
            }
            if (step == 31) {
                // epilogue: relu(acc+bm2), mask j!=i, pair-reduce, accumulate into bH
                const int iG = ch*8 + ep_iL;
                const int cb = e_cg*16;
                float part[16];
#pragma unroll
                for (int c=0;c<16;++c) part[c]=0.f;
#pragma unroll
                for (int m=0;m<8;++m) {
                    const float msk = (ep_jB + m == iG) ? 0.f : 1.f;
#pragma unroll
                    for (int c=0;c<16;++c)
                        part[c] += msk * fmaxf(eacc[m][c] + bm2[cb+c], 0.f);
                }
#pragma unroll
                for (int c=0;c<16;++c) part[c] += __shfl_xor(part[c], 16);
                if ((e_rg & 1) == 0) {
#pragma unroll
                    for (int v=0; v<4; ++v) {
                        float4v h = ld4(bH + iG*STR + cb + v*4);
#pragma unroll
                        for (int c=0;c<4;++c) h[c] += part[v*4+c];
                        st4(bH + iG*STR + cb + v*4, h);
                    }
                }
#pragma unroll
                for (int m=0;m<8;++m)
#pragma unroll
                    for (int c=0;c<16;++c) eacc[m][c]=0.f;
            }
            if (g < 63) {   // write prefetched tile (vmcnt drain lands here, after FMAs)
                st4(&BTB[bufn][ sb_kt   *256 + sb_phys], pb0);
                st4(&BTB[bufn][(sb_kt+4)*256 + sb_phys], pb1);
                st4(&ATB[bufn][sa_kt*128 + sa_r0], pav);
            }
            __syncthreads();
        }

        // ---- node update: h' = relu(x@Wu1+bu1)@Wu2 + bu2 ----
        sgemm16<true ,true>(bH, Wu1, bu1, bP, AtSd, tid);   // y  -> bP
        sgemm16<false,true>(bP, Wu2, bu2, bH, AtSd, tid);   // h' -> bH
    }

    // ---- output head ----
    sgemm16<true,true>(bH, Wo1, bo1, bP, AtSd, tid);        // y2 -> bP
    __syncthreads();
    {
        const int r = tid >> 4, u = tid & 15;
        float partial = 0.f;
#pragma unroll
        for (int t2 = 0; t2 < 16; ++t2)
            partial = fmaf(bP[r*STR + u*16 + t2], Wo2[u*16 + t2], partial);
        partial += __shfl_xor(partial, 1);
        partial += __shfl_xor(partial, 2);
        partial += __shfl_xor(partial, 4);
        partial += __shfl_xor(partial, 8);
        if (u == 0) LG[r] = partial + bo2[0];
    }
    __syncthreads();
    if (tid == 0) {
        float pr = 1.f;
#pragma unroll
        for (int i = 0; i < 16; ++i)
            pr *= 1.f / (1.f + expf(-LG[i]));
        out[gid] = pr;
    }
}

extern "C" void kernel_launch(void* const* d_in, const int* in_sizes, int n_in,
                              void* d_out, int out_size, void* d_ws, size_t ws_size,
                              hipStream_t stream)
{
    (void)in_sizes; (void)n_in; (void)out_size; (void)d_ws; (void)ws_size;
    fcgn_kernel<<<dim3(NGRAPH), dim3(256), 0, stream>>>(
        (const float*)d_in[0],  (const float*)d_in[1],  (const float*)d_in[2],
        (const float*)d_in[3],  (const float*)d_in[4],  (const float*)d_in[5],
        (const float*)d_in[6],  (const float*)d_in[7],  (const float*)d_in[8],
        (const float*)d_in[9],  (const float*)d_in[10], (const float*)d_in[11],
        (const float*)d_in[12], (const float*)d_in[13], (const float*)d_in[14],
        (const int*)d_in[15],   (float*)d_out);
}

// Round 5
// 1257.687 us; speedup vs baseline: 2.1560x; 2.1560x over previous
//
#include <hip/hip_runtime.h>

#define STR 260          // padded row stride (floats); 260%32=4 -> 2-way column reads
#define NGRAPH 512

typedef float float4v __attribute__((ext_vector_type(4)));
typedef float float2v __attribute__((ext_vector_type(2)));

static __device__ __forceinline__ float4v ld4(const float* p){ return *(const float4v*)p; }
static __device__ __forceinline__ void st4(float* p, float4v v){ *(float4v*)p = v; }
static __device__ __forceinline__ void st2(float* p, float2v v){ *(float2v*)p = v; }

// ---------------- single 16x256x256 GEMM: C = act(A @ Bg + bias) ----------------
// split-K-4 over lane quads, 8x8 tiles, k-step 8 (8 barriers), B from global with
// register rotation (next-kt loads issued before current FMAs), A^T double-buffered.
// ~105 live VGPRs — stays inside the 128-VGPR no-spill envelope.
template<bool RELU, bool HASBIAS>
__device__ __forceinline__ void sgemm16(const float* __restrict__ A,
                                        const float* __restrict__ Bg,
                                        const float* __restrict__ bias,
                                        float* __restrict__ C,
                                        float* __restrict__ AtSd,
                                        int tid)
{
    const int s  = tid & 3;            // K-slice (64 k each)
    const int cg = (tid >> 2) & 31;    // 8 cols
    const int rg = tid >> 7;           // 8 rows
    const int w_kt = tid & 7, w_ss = (tid >> 3) & 3, w_r = tid >> 5;   // stage map
    const int idxw = w_kt*84 + w_ss*21 + w_r;
    const int rB0  = w_r*STR + w_ss*64 + w_kt;
    const int rB1  = rB0 + 8*STR;

    __syncthreads();                   // A (LDS) written by previous phase
    AtSd[idxw]     = A[rB0];
    AtSd[idxw + 8] = A[rB1];
    __syncthreads();

    float acc[8][8];
#pragma unroll
    for (int m=0;m<8;++m)
#pragma unroll
        for (int c=0;c<8;++c) acc[m][c]=0.f;

    const float* bcol = Bg + s*64*256 + cg*8;
    for (int step = 0; step < 8; ++step) {
        const float* cur = AtSd + (step&1)*672;
        float nxt0 = 0.f, nxt1 = 0.f;
        if (step < 7) { nxt0 = A[rB0 + (step+1)*8]; nxt1 = A[rB1 + (step+1)*8]; }
        const float* bbase = bcol + step*8*256;
        float4v b0 = ld4(bbase), b1 = ld4(bbase + 4);
#pragma unroll
        for (int kt = 0; kt < 8; ++kt) {
            float4v cb0 = b0, cb1 = b1;
            if (kt < 7) { b0 = ld4(bbase + (kt+1)*256); b1 = ld4(bbase + (kt+1)*256 + 4); }
            const float* ap = cur + kt*84 + s*21 + rg*8;
            float4v a0 = ld4(ap), a1 = ld4(ap+4);
            float a[8] = {a0[0],a0[1],a0[2],a0[3],a1[0],a1[1],a1[2],a1[3]};
            float b[8] = {cb0[0],cb0[1],cb0[2],cb0[3],cb1[0],cb1[1],cb1[2],cb1[3]};
#pragma unroll
            for (int m=0;m<8;++m)
#pragma unroll
                for (int c=0;c<8;++c) acc[m][c] = fmaf(a[m], b[c], acc[m][c]);
        }
        if (step < 7) {
            float* nx = AtSd + ((step+1)&1)*672;
            nx[idxw] = nxt0; nx[idxw + 8] = nxt1;
        }
        __syncthreads();
    }
#pragma unroll
    for (int m=0;m<8;++m)
#pragma unroll
        for (int c=0;c<8;++c) {
            float v = acc[m][c];
            v += __shfl_xor(v,1);
            v += __shfl_xor(v,2);
            acc[m][c] = v;
        }
    if (s == 0) {
        const int c0 = cg*8;
#pragma unroll
        for (int m=0;m<8;++m) {
            float o[8];
#pragma unroll
            for (int c=0;c<8;++c) {
                float v = acc[m][c];
                if (HASBIAS) v += bias[c0+c];
                if (RELU)    v = fmaxf(v,0.f);
                o[c] = v;
            }
            st4(C + (rg*8+m)*STR + c0,     (float4v){o[0],o[1],o[2],o[3]});
            st4(C + (rg*8+m)*STR + c0 + 4, (float4v){o[4],o[5],o[6],o[7]});
        }
    }
    // no trailing sync; every consumer phase begins with __syncthreads()
}

__global__ __launch_bounds__(256, 2)
void fcgn_kernel(const float* __restrict__ towers, const float* __restrict__ We,
                 const float* __restrict__ be,  const float* __restrict__ Wm1,
                 const float* __restrict__ bm1, const float* __restrict__ Wm2,
                 const float* __restrict__ bm2, const float* __restrict__ Wu1,
                 const float* __restrict__ bu1, const float* __restrict__ Wu2,
                 const float* __restrict__ bu2, const float* __restrict__ Wo1,
                 const float* __restrict__ bo1, const float* __restrict__ Wo2,
                 const float* __restrict__ bo2, const int* __restrict__ kPtr,
                 float* __restrict__ out)
{
    __shared__ alignas(16) float bH[16*STR];      // h -> x -> h'
    __shared__ alignas(16) float bP[16*STR];      // p / y
    __shared__ alignas(16) float bQ[16*STR];      // q
    __shared__ alignas(16) float BTB[2][8*256];   // edge Wm2 tile (XOR-swizzled 16B slots)
    __shared__ alignas(16) float ATB[2][8*64];    // edge relu(p_i+q_j)^T tile (64 pair-rows)
    __shared__ alignas(16) float AtSd[2*672];     // sgemm A^T tiles
    __shared__ float TW[224];
    __shared__ float LG[16];

    const int gid = blockIdx.x;
    const int tid = threadIdx.x;

    if (tid < 224) TW[tid] = towers[gid*224 + tid];
    __syncthreads();

    // ---- encoder: h = towers @ We + be ----
    {
        const int r = tid >> 4, u = tid & 15;
        for (int cc = 0; cc < 16; ++cc) {
            const int c = cc*16 + u;
            float sum = be[c];
#pragma unroll
            for (int f = 0; f < 14; ++f)
                sum = fmaf(TW[r*14 + f], We[f*256 + c], sum);
            bH[r*STR + c] = sum;
        }
    }

    int kk = kPtr[0];
    if (kk < 0) kk = 0;
    if (kk > 8) kk = 8;   // defensive: garbage k must not hang the GPU

    // ---- edge-phase thread mappings (8x8 tiles, 64-row chunks) ----
    const int e_rg = tid >> 5;     // 8 rowgroups of 8 pair-rows
    const int e_cg = tid & 31;     // 32 colgroups of 8 cols
    const int sl0 = 2*e_cg, sl1 = 2*e_cg + 1;
    const int off0 = (sl0 ^ ((sl0>>3)&7))*4;     // XOR-swizzled 16B-slot offsets (floats)
    const int off1 = (sl1 ^ ((sl1>>3)&7))*4;
    const int sb_kt   = tid >> 6;                 // B stage: rows kt, kt+4
    const int sb_sl   = tid & 63;
    const int sb_phys = (sb_sl ^ ((sb_sl>>3)&7))*4;
    const int sa_kt   = tid >> 5;                 // A^T stage: k-row, pair-rows r0,r0+1
    const int sa_r0   = (tid & 31)*2;
    const int sa_j0   = sa_r0 & 15;
    const int sa_il   = sa_r0 >> 4;
    const int ep_iL   = e_rg >> 1;                // epilogue mapping
    const int ep_jB   = (e_rg & 1)*8;

    for (int rnd = 0; rnd < kk; ++rnd) {
        // p = h @ Wm1[:256] ; q = h @ Wm1[256:] + bm1
        sgemm16<false,false>(bH, Wm1,           nullptr, bP, AtSd, tid);
        sgemm16<false,true >(bH, Wm1 + 256*256, bm1,     bQ, AtSd, tid);

        // ---- edge GEMM: 256 pair-rows x 256 cols; 4 chunks x 32 k-steps of 8 ----
        __syncthreads();               // p,q visible
        {   // prologue: stage g=0 (ch=0, ks=0)
            st4(&BTB[0][ sb_kt   *256 + sb_phys], ld4(Wm2 +  sb_kt   *256 + sb_sl*4));
            st4(&BTB[0][(sb_kt+4)*256 + sb_phys], ld4(Wm2 + (sb_kt+4)*256 + sb_sl*4));
            const float pv = bP[sa_il*STR + sa_kt];
            const float v0 = fmaxf(pv + bQ[ sa_j0   *STR + sa_kt], 0.f);
            const float v1 = fmaxf(pv + bQ[(sa_j0+1)*STR + sa_kt], 0.f);
            st2(&ATB[0][sa_kt*64 + sa_r0], (float2v){v0, v1});
        }
        __syncthreads();

        float eacc[8][8];
#pragma unroll
        for (int m=0;m<8;++m)
#pragma unroll
            for (int c=0;c<8;++c) eacc[m][c]=0.f;

        for (int g = 0; g < 128; ++g) {
            const int buf = g & 1;
            const int ch = g >> 5, step = g & 31;
            // T14: issue next-tile loads into registers BEFORE the FMA block
            float4v pb0, pb1;
            float pa0 = 0.f, pa1 = 0.f;
            const int gn = g + 1, bufn = gn & 1;
            if (g < 127) {
                const int chn = gn >> 5, ksn = (gn & 31)*8;
                pb0 = ld4(Wm2 + (ksn + sb_kt  )*256 + sb_sl*4);
                pb1 = ld4(Wm2 + (ksn + sb_kt+4)*256 + sb_sl*4);
                const int k0 = ksn + sa_kt;
                const float pv = bP[(chn*4 + sa_il)*STR + k0];
                pa0 = fmaxf(pv + bQ[ sa_j0   *STR + k0], 0.f);
                pa1 = fmaxf(pv + bQ[(sa_j0+1)*STR + k0], 0.f);
            }
            // compute 8 kt x (8x8) FMA on buf — covers the L2 latency of pb0/pb1
#pragma unroll
            for (int kt = 0; kt < 8; ++kt) {
                const float* ap = &ATB[buf][kt*64 + e_rg*8];
                const float* bb = &BTB[buf][kt*256];
                float4v a0 = ld4(ap), a1 = ld4(ap+4);
                float4v b0 = ld4(bb + off0), b1 = ld4(bb + off1);
                float a[8] = {a0[0],a0[1],a0[2],a0[3],a1[0],a1[1],a1[2],a1[3]};
                float b[8] = {b0[0],b0[1],b0[2],b0[3],b1[0],b1[1],b1[2],b1[3]};
#pragma unroll
                for (int m=0;m<8;++m)
#pragma unroll
                    for (int c=0;c<8;++c) eacc[m][c] = fmaf(a[m], b[c], eacc[m][c]);
            }
            if (step == 31) {
                // epilogue: relu(acc+bm2), mask j!=i, pair-reduce, accumulate into bH
                const int iG = ch*4 + ep_iL;
                const int cb = e_cg*8;
                float part[8];
#pragma unroll
                for (int c=0;c<8;++c) part[c]=0.f;
#pragma unroll
                for (int m=0;m<8;++m) {
                    const float msk = (ep_jB + m == iG) ? 0.f : 1.f;
#pragma unroll
                    for (int c=0;c<8;++c)
                        part[c] += msk * fmaxf(eacc[m][c] + bm2[cb+c], 0.f);
                }
#pragma unroll
                for (int c=0;c<8;++c) part[c] += __shfl_xor(part[c], 32);
                if ((e_rg & 1) == 0) {      // single owner per (iG, col-octet) -> plain RMW
                    float4v h0 = ld4(bH + iG*STR + cb);
                    float4v h1 = ld4(bH + iG*STR + cb + 4);
#pragma unroll
                    for (int c=0;c<4;++c){ h0[c]+=part[c]; h1[c]+=part[c+4]; }
                    st4(bH + iG*STR + cb,     h0);
                    st4(bH + iG*STR + cb + 4, h1);
                }
#pragma unroll
                for (int m=0;m<8;++m)
#pragma unroll
                    for (int c=0;c<8;++c) eacc[m][c]=0.f;
            }
            if (g < 127) {   // vmcnt drain lands here, AFTER the FMAs
                st4(&BTB[bufn][ sb_kt   *256 + sb_phys], pb0);
                st4(&BTB[bufn][(sb_kt+4)*256 + sb_phys], pb1);
                st2(&ATB[bufn][sa_kt*64 + sa_r0], (float2v){pa0, pa1});
            }
            __syncthreads();
        }

        // ---- node update: h' = relu(x@Wu1+bu1)@Wu2 + bu2 ----
        sgemm16<true ,true>(bH, Wu1, bu1, bP, AtSd, tid);   // y  -> bP
        sgemm16<false,true>(bP, Wu2, bu2, bH, AtSd, tid);   // h' -> bH
    }

    // ---- output head ----
    sgemm16<true,true>(bH, Wo1, bo1, bP, AtSd, tid);        // y2 -> bP
    __syncthreads();
    {
        const int r = tid >> 4, u = tid & 15;
        float partial = 0.f;
#pragma unroll
        for (int t2 = 0; t2 < 16; ++t2)
            partial = fmaf(bP[r*STR + u*16 + t2], Wo2[u*16 + t2], partial);
        partial += __shfl_xor(partial, 1);
        partial += __shfl_xor(partial, 2);
        partial += __shfl_xor(partial, 4);
        partial += __shfl_xor(partial, 8);
        if (u == 0) LG[r] = partial + bo2[0];
    }
    __syncthreads();
    if (tid == 0) {
        float pr = 1.f;
#pragma unroll
        for (int i = 0; i < 16; ++i)
            pr *= 1.f / (1.f + expf(-LG[i]));
        out[gid] = pr;
    }
}

extern "C" void kernel_launch(void* const* d_in, const int* in_sizes, int n_in,
                              void* d_out, int out_size, void* d_ws, size_t ws_size,
                              hipStream_t stream)
{
    (void)in_sizes; (void)n_in; (void)out_size; (void)d_ws; (void)ws_size;
    fcgn_kernel<<<dim3(NGRAPH), dim3(256), 0, stream>>>(
        (const float*)d_in[0],  (const float*)d_in[1],  (const float*)d_in[2],
        (const float*)d_in[3],  (const float*)d_in[4],  (const float*)d_in[5],
        (const float*)d_in[6],  (const float*)d_in[7],  (const float*)d_in[8],
        (const float*)d_in[9],  (const float*)d_in[10], (const float*)d_in[11],
        (const float*)d_in[12], (const float*)d_in[13], (const float*)d_in[14],
        (const int*)d_in[15],   (float*)d_out);
}